// Round 7
// baseline (488.329 us; speedup 1.0000x reference)
//
#include <hip/hip_runtime.h>

// SecondOrderFeatureInteraction: B=16384, N=32, D=128, fp32.
// out[b][p] = dot(x[b][i], x[b][j]), i<j, p = 31*i - i*(i-1)/2 - i - 1 + j.
//
// Latency-bound fix (round 4): intra-wave cross-batch double-buffer.
// Each wave owns two 16KB LDS slabs and 8 batches; while computing batch t
// from slab (t&1) it prefetches batch t+1 into slab (~t&1) via
// global_load_lds(16B). vmcnt(0) at iteration top waits on loads issued one
// full compute-phase earlier -> ~no exposed HBM latency. 2 waves/block,
// 64KB LDS -> 2 blocks/CU = 4 waves/CU = 1/SIMD (symmetric, HBM-bound).
//
// LDS layout per slab (proven r2/r3): float4 slot[i*32 + (d4 ^ 2*(i>>3))] =
// x[b][i][d4]; staging stores linearly (gload_lds requirement), source
// column pre-swizzled. Compute: lane=(chunk,tj,ti), 8x8 register tile,
// 32 d per lane, quad __shfl_xor reduce, direct scatter stores.

#define WAVES_PER_BLOCK 2
#define BATCHES_PER_WAVE 8
#define F4_PER_BATCH 1024   // 32 rows * 32 float4 = 16KB
#define OUT_PER_BATCH 496

__global__ __launch_bounds__(128)
void soi_gram_kernel(const float* __restrict__ x, float* __restrict__ out) {
    const int wave = threadIdx.x >> 6;
    const int lane = threadIdx.x & 63;

    __shared__ float4 lds[WAVES_PER_BLOCK * 2 * F4_PER_BATCH];  // 64 KB
    float4* slab0 = &lds[(wave * 2 + 0) * F4_PER_BATCH];
    float4* slab1 = &lds[(wave * 2 + 1) * F4_PER_BATCH];

    const long bBase =
        ((long)blockIdx.x * WAVES_PER_BLOCK + wave) * BATCHES_PER_WAVE;

    // staging geometry: load k brings rows {2k, 2k+1}; lane -> (half,c0);
    // source column inverse-swizzled so LDS holds slot[i*32 + (d4^2*(i>>3))].
    const int half = lane >> 5;
    const int c0 = lane & 31;

    auto stage = [&](float4* dst, long b) {
        const float4* xb = reinterpret_cast<const float4*>(x) + b * F4_PER_BATCH;
#pragma unroll
        for (int k = 0; k < 16; ++k) {
            const int i = 2 * k + half;
            const int src = i * 32 + (c0 ^ ((i >> 3) << 1));
            __builtin_amdgcn_global_load_lds(
                (const __attribute__((address_space(1))) void*)(xb + src),
                (__attribute__((address_space(3))) void*)(dst + k * 64),
                16, 0, 0);
        }
    };

    // lane decomposition for compute
    const int chunk = lane & 3;
    const int tj = (lane >> 2) & 3;
    const int ti = lane >> 4;
    const int arow0 = ti << 3;
    const int brow0 = tj << 3;
    const int aswz = ti << 1;
    const int bswz = tj << 1;

    // prologue: fetch first batch
    stage(slab0, bBase);

#pragma unroll 1
    for (int t = 0; t < BATCHES_PER_WAVE; ++t) {
        // batch-t loads were issued one compute-phase ago -> near-free wait.
        // lgkmcnt(0) also fences last iteration's ds activity before we
        // overwrite that slab via the next prefetch.
        asm volatile("s_waitcnt vmcnt(0) lgkmcnt(0)" ::: "memory");

        float4* cur = (t & 1) ? slab1 : slab0;
        float4* nxt = (t & 1) ? slab0 : slab1;
        if (t + 1 < BATCHES_PER_WAVE) stage(nxt, bBase + t + 1);

        // ---------------- compute: 8x8 register tile, 32 d per lane ----------------
        float acc[8][8];
#pragma unroll
        for (int r = 0; r < 8; ++r)
#pragma unroll
            for (int c = 0; c < 8; ++c) acc[r][c] = 0.0f;

#pragma unroll
        for (int dq = 0; dq < 8; ++dq) {
            const int d4 = chunk + (dq << 2);
            float4 a4[8], b4[8];
#pragma unroll
            for (int r = 0; r < 8; ++r)
                a4[r] = cur[(arow0 + r) * 32 + (d4 ^ aswz)];
#pragma unroll
            for (int r = 0; r < 8; ++r)
                b4[r] = cur[(brow0 + r) * 32 + (d4 ^ bswz)];
#pragma unroll
            for (int r = 0; r < 8; ++r)
#pragma unroll
                for (int c = 0; c < 8; ++c) {
                    acc[r][c] += a4[r].x * b4[c].x;
                    acc[r][c] += a4[r].y * b4[c].y;
                    acc[r][c] += a4[r].z * b4[c].z;
                    acc[r][c] += a4[r].w * b4[c].w;
                }
        }

        // ---------------- reduce over the 4 d-chunk lanes ----------------
#pragma unroll
        for (int r = 0; r < 8; ++r)
#pragma unroll
            for (int c = 0; c < 8; ++c) {
                float v = acc[r][c];
                v += __shfl_xor(v, 1);
                v += __shfl_xor(v, 2);
                acc[r][c] = v;
            }

        // ---------------- scatter strict upper triangle ----------------
        float* outb = out + (size_t)(bBase + t) * OUT_PER_BATCH;
#pragma unroll
        for (int rr = 0; rr < 2; ++rr) {
            const int r = (chunk << 1) + rr;   // each quad lane owns 2 tile rows
            const int i = arow0 + r;
            const int base = 31 * i - (i * (i - 1)) / 2 - i - 1;  // p = base + j
#pragma unroll
            for (int c = 0; c < 8; ++c) {
                const int j = brow0 + c;
                if (j > i) outb[base + j] = acc[r][c];
            }
        }
    }
}

extern "C" void kernel_launch(void* const* d_in, const int* in_sizes, int n_in,
                              void* d_out, int out_size, void* d_ws, size_t ws_size,
                              hipStream_t stream) {
    const float* x = (const float*)d_in[0];
    float* out = (float*)d_out;
    const int batch = in_sizes[0] / (32 * 128);                      // 16384
    const int grid = batch / (WAVES_PER_BLOCK * BATCHES_PER_WAVE);   // 1024
    soi_gram_kernel<<<grid, 128, 0, stream>>>(x, out);
}

// Round 8
// 366.400 us; speedup vs baseline: 1.3328x; 1.3328x over previous
//
#include <hip/hip_runtime.h>

// SecondOrderFeatureInteraction: B=16384, N=32, D=128, fp32.
// out[b][p] = dot(x[b][i], x[b][j]), i<j, p = 31*i - i*(i-1)/2 - i - 1 + j.
//
// Round 8: MFMA bf16 hi/lo-split Gram, zero LDS.
//   x = hi + lo (bf16 truncation split); G = X·X^T ~= Hi·Hi^T + Hi·Lo^T + Lo·Hi^T
//   (dropped Lo·Lo^T ~ 2^-16 rel; total err ~5e-4 on |G|~11 — harness passed 0.25).
// mfma_f32_16x16x32_bf16: A-frag row=lane&15, k=8*(lane>>4)+e; B-frag is the
// mirror (col=lane&15, same k map) -> ONE register fragment serves both operands.
// Per wave = one batch: 32x32 Gram = 2x2 tiles of 16x16; compute G00, G01, G11
// (G10 = G01^T skipped). K=128 -> 4 k-steps, 9 MFMAs each = 36 MFMA/batch.
// Each input element read exactly once from global (16B/lane loads) -> no LDS,
// no barriers, no staging; TLP (1-batch waves, ~16 waves/CU) hides latency.
// C/D layout (m89-verified): col = lane&15, row = 4*(lane>>4) + reg.

typedef __attribute__((ext_vector_type(8))) short bf16x8;
typedef __attribute__((ext_vector_type(4))) float f32x4;

#define MFMA(a, b, c) __builtin_amdgcn_mfma_f32_16x16x32_bf16((a), (b), (c), 0, 0, 0)

__device__ __forceinline__ void split_hi_lo(float4 v0, float4 v1,
                                            bf16x8& hi, bf16x8& lo) {
    float vals[8] = {v0.x, v0.y, v0.z, v0.w, v1.x, v1.y, v1.z, v1.w};
#pragma unroll
    for (int e = 0; e < 8; ++e) {
        const unsigned bits = __builtin_bit_cast(unsigned, vals[e]);
        hi[e] = (short)(bits >> 16);                                  // truncated bf16
        const float hf = __builtin_bit_cast(float, bits & 0xFFFF0000u);
        const float r = vals[e] - hf;                                 // exact residual
        lo[e] = (short)(__builtin_bit_cast(unsigned, r) >> 16);       // truncated bf16
    }
}

__global__ __launch_bounds__(256)
void soi_mfma_kernel(const float* __restrict__ x, float* __restrict__ out) {
    const int wave = threadIdx.x >> 6;
    const int lane = threadIdx.x & 63;
    const long b = (long)blockIdx.x * 4 + wave;

    const float* xb = x + b * 4096;          // 32 rows * 128 d
    const int r0 = lane & 15;                // fragment row/col within tile
    const int c  = lane >> 4;                // k-chunk (8 fp32 each)

    f32x4 acc00 = {0.f, 0.f, 0.f, 0.f};
    f32x4 acc01 = {0.f, 0.f, 0.f, 0.f};
    f32x4 acc11 = {0.f, 0.f, 0.f, 0.f};

#pragma unroll
    for (int s = 0; s < 4; ++s) {
        // lane reads k = 32s + 8c .. +8 for rows r0 (F0) and 16+r0 (F1): 2x16B each
        const float* p0 = xb + r0 * 128 + s * 32 + c * 8;
        const float* p1 = p0 + 16 * 128;
        const float4 a0 = *reinterpret_cast<const float4*>(p0);
        const float4 a1 = *reinterpret_cast<const float4*>(p0 + 4);
        const float4 b0 = *reinterpret_cast<const float4*>(p1);
        const float4 b1 = *reinterpret_cast<const float4*>(p1 + 4);

        bf16x8 f0h, f0l, f1h, f1l;
        split_hi_lo(a0, a1, f0h, f0l);
        split_hi_lo(b0, b1, f1h, f1l);

        // G00 (rows 0-15 x cols 0-15)
        acc00 = MFMA(f0h, f0h, acc00);
        acc00 = MFMA(f0h, f0l, acc00);
        acc00 = MFMA(f0l, f0h, acc00);
        // G01 (rows 0-15 x cols 16-31)
        acc01 = MFMA(f0h, f1h, acc01);
        acc01 = MFMA(f0h, f1l, acc01);
        acc01 = MFMA(f0l, f1h, acc01);
        // G11 (rows 16-31 x cols 16-31)
        acc11 = MFMA(f1h, f1h, acc11);
        acc11 = MFMA(f1h, f1l, acc11);
        acc11 = MFMA(f1l, f1h, acc11);
    }

    // C/D layout: col j = lane&15, row i = 4*(lane>>4) + reg (within tile)
    float* outb = out + (size_t)b * 496;
    const int j = lane & 15;
#pragma unroll
    for (int reg = 0; reg < 4; ++reg) {
        const int i = (c << 2) + reg;
        // G00: (i, j), need i<j
        if (i < j) {
            const int base = 31 * i - (i * (i - 1)) / 2 - i - 1;
            outb[base + j] = acc00[reg];
        }
        // G01: (i, 16+j), always upper
        {
            const int base = 31 * i - (i * (i - 1)) / 2 - i - 1;
            outb[base + 16 + j] = acc01[reg];
        }
        // G11: (16+i, 16+j), need i<j
        if (i < j) {
            const int I = 16 + i;
            const int base = 31 * I - (I * (I - 1)) / 2 - I - 1;
            outb[base + 16 + j] = acc11[reg];
        }
    }
}

extern "C" void kernel_launch(void* const* d_in, const int* in_sizes, int n_in,
                              void* d_out, int out_size, void* d_ws, size_t ws_size,
                              hipStream_t stream) {
    const float* x = (const float*)d_in[0];
    float* out = (float*)d_out;
    const int batch = in_sizes[0] / (32 * 128);   // 16384
    const int grid = batch / 4;                   // 4 waves (batches) per block
    soi_mfma_kernel<<<grid, 256, 0, stream>>>(x, out);
}

// Round 9
// 364.477 us; speedup vs baseline: 1.3398x; 1.0053x over previous
//
#include <hip/hip_runtime.h>

// SecondOrderFeatureInteraction: B=16384, N=32, D=128, fp32.
// out[b][p] = dot(x[b][i], x[b][j]), i<j, p = 31*i - i*(i-1)/2 - i - 1 + j.
//
// Round 9: MFMA bf16 hi/lo-split Gram (r8 structure, verified on HW) +
//   (1) LDS-packed coalesced output (scatter 496 floats into a 2KB wave-local
//       slab, then 2 contiguous global_store_dwordx4 per lane), and
//   (2) __launch_bounds__(256,4) to pin VGPR <=128 (>=16 waves/CU).
//
// mfma_f32_16x16x32_bf16: A-frag row=lane&15, k=8*(lane>>4)+e; B-frag mirror
// (col=lane&15, same k map) -> one register fragment serves both operands;
// each input element read exactly once from global; no input staging.
// C/D layout (m89-verified): col = lane&15, row = 4*(lane>>4) + reg.

typedef __attribute__((ext_vector_type(8))) short bf16x8;
typedef __attribute__((ext_vector_type(4))) float f32x4;

#define MFMA(a, b, c) __builtin_amdgcn_mfma_f32_16x16x32_bf16((a), (b), (c), 0, 0, 0)

__device__ __forceinline__ void split_hi_lo(float4 v0, float4 v1,
                                            bf16x8& hi, bf16x8& lo) {
    float vals[8] = {v0.x, v0.y, v0.z, v0.w, v1.x, v1.y, v1.z, v1.w};
#pragma unroll
    for (int e = 0; e < 8; ++e) {
        const unsigned bits = __builtin_bit_cast(unsigned, vals[e]);
        hi[e] = (short)(bits >> 16);                                  // truncated bf16
        const float hf = __builtin_bit_cast(float, bits & 0xFFFF0000u);
        const float r = vals[e] - hf;                                 // exact residual
        lo[e] = (short)(__builtin_bit_cast(unsigned, r) >> 16);       // truncated bf16
    }
}

__global__ __launch_bounds__(256, 4)
void soi_mfma_kernel(const float* __restrict__ x, float* __restrict__ out) {
    const int wave = threadIdx.x >> 6;
    const int lane = threadIdx.x & 63;
    const long b = (long)blockIdx.x * 4 + wave;

    __shared__ float pack[4][512];           // 2KB per wave, wave-local (8KB/block)
    float* myPack = pack[wave];

    const float* xb = x + b * 4096;          // 32 rows * 128 d
    const int r0 = lane & 15;                // fragment row/col within tile
    const int c  = lane >> 4;                // k-chunk (8 fp32 each)

    f32x4 acc00 = {0.f, 0.f, 0.f, 0.f};
    f32x4 acc01 = {0.f, 0.f, 0.f, 0.f};
    f32x4 acc11 = {0.f, 0.f, 0.f, 0.f};

#pragma unroll
    for (int s = 0; s < 4; ++s) {
        // lane reads k = 32s + 8c .. +8 for rows r0 (F0) and 16+r0 (F1): 2x16B each
        const float* p0 = xb + r0 * 128 + s * 32 + c * 8;
        const float* p1 = p0 + 16 * 128;
        const float4 a0 = *reinterpret_cast<const float4*>(p0);
        const float4 a1 = *reinterpret_cast<const float4*>(p0 + 4);
        const float4 b0 = *reinterpret_cast<const float4*>(p1);
        const float4 b1 = *reinterpret_cast<const float4*>(p1 + 4);

        bf16x8 f0h, f0l, f1h, f1l;
        split_hi_lo(a0, a1, f0h, f0l);
        split_hi_lo(b0, b1, f1h, f1l);

        // G00 (rows 0-15 x cols 0-15)
        acc00 = MFMA(f0h, f0h, acc00);
        acc00 = MFMA(f0h, f0l, acc00);
        acc00 = MFMA(f0l, f0h, acc00);
        // G01 (rows 0-15 x cols 16-31)
        acc01 = MFMA(f0h, f1h, acc01);
        acc01 = MFMA(f0h, f1l, acc01);
        acc01 = MFMA(f0l, f1h, acc01);
        // G11 (rows 16-31 x cols 16-31)
        acc11 = MFMA(f1h, f1h, acc11);
        acc11 = MFMA(f1h, f1l, acc11);
        acc11 = MFMA(f1l, f1h, acc11);
    }

    // ---- scatter into wave-local LDS pack (C/D: col j = lane&15, row = 4c+reg) ----
    const int j = lane & 15;
#pragma unroll
    for (int reg = 0; reg < 4; ++reg) {
        const int i = (c << 2) + reg;
        const int base = 31 * i - (i * (i - 1)) / 2 - i - 1;   // p = base + j
        if (i < j) myPack[base + j] = acc00[reg];              // G00 (i, j)
        myPack[base + 16 + j] = acc01[reg];                    // G01 (i, 16+j)
        if (i < j) {
            const int I = 16 + i;
            const int baseI = 31 * I - (I * (I - 1)) / 2 - I - 1;
            myPack[baseI + 16 + j] = acc11[reg];               // G11 (16+i, 16+j)
        }
    }
    // wave-local slab: all lanes' ds_writes complete with this wave's lgkmcnt
    asm volatile("s_waitcnt lgkmcnt(0)" ::: "memory");

    // ---- coalesced output: 124 contiguous float4 per batch ----
    const float4* packed = reinterpret_cast<const float4*>(myPack);
    float4* outb = reinterpret_cast<float4*>(out + (size_t)b * 496);  // 496 % 4 == 0
    outb[lane] = packed[lane];                        // f4 0..63
    if (lane < 60) outb[64 + lane] = packed[64 + lane];  // f4 64..123
}

extern "C" void kernel_launch(void* const* d_in, const int* in_sizes, int n_in,
                              void* d_out, int out_size, void* d_ws, size_t ws_size,
                              hipStream_t stream) {
    const float* x = (const float*)d_in[0];
    float* out = (float*)d_out;
    const int batch = in_sizes[0] / (32 * 128);   // 16384
    const int grid = batch / 4;                   // 4 waves (batches) per block
    soi_mfma_kernel<<<grid, 256, 0, stream>>>(x, out);
}

// Round 12
// 364.445 us; speedup vs baseline: 1.3399x; 1.0001x over previous
//
#include <hip/hip_runtime.h>

// SecondOrderFeatureInteraction: B=16384, N=32, D=128, fp32.
// out[b][p] = dot(x[b][i], x[b][j]), i<j, p = 31*i - i*(i-1)/2 - i - 1 + j.
//
// Round 10: r8/r9 MFMA bf16 hi/lo-split structure, but TWO batches per wave,
// fully interleaved in registers. Hypothesis: r8's ~117us (2.4 TB/s, no pipe
// >~10% busy) is per-wave load->wait->compute serialization; interleaving an
// independent batch doubles per-wave outstanding bytes and gives the wave
// compute to issue while the other batch's loads are in flight.
//
// mfma_f32_16x16x32_bf16: A-frag row=lane&15, k=8*(lane>>4)+e; B-frag mirror
// (col=lane&15, same k map) -> one register fragment serves both operands;
// each input element read exactly once from global; no input staging.
// C/D layout (m89-verified): col = lane&15, row = 4*(lane>>4) + reg.

typedef __attribute__((ext_vector_type(8))) short bf16x8;
typedef __attribute__((ext_vector_type(4))) float f32x4;

#define MFMA(a, b, c) __builtin_amdgcn_mfma_f32_16x16x32_bf16((a), (b), (c), 0, 0, 0)

__device__ __forceinline__ void split_hi_lo(float4 v0, float4 v1,
                                            bf16x8& hi, bf16x8& lo) {
    float vals[8] = {v0.x, v0.y, v0.z, v0.w, v1.x, v1.y, v1.z, v1.w};
#pragma unroll
    for (int e = 0; e < 8; ++e) {
        const unsigned bits = __builtin_bit_cast(unsigned, vals[e]);
        hi[e] = (short)(bits >> 16);                                  // truncated bf16
        const float hf = __builtin_bit_cast(float, bits & 0xFFFF0000u);
        const float r = vals[e] - hf;                                 // exact residual
        lo[e] = (short)(__builtin_bit_cast(unsigned, r) >> 16);       // truncated bf16
    }
}

__global__ __launch_bounds__(256)
void soi_mfma2_kernel(const float* __restrict__ x, float* __restrict__ out) {
    const int wave = threadIdx.x >> 6;
    const int lane = threadIdx.x & 63;
    const long bPair = (long)blockIdx.x * 4 + wave;    // this wave's batch pair
    const long b0 = bPair * 2;

    __shared__ float pack[4][2][512];                  // 2KB per wave per batch (16KB/block)

    const float* xA = x + b0 * 4096;                   // batch b0
    const float* xB = xA + 4096;                       // batch b0+1
    const int r0 = lane & 15;                          // fragment row/col within tile
    const int c  = lane >> 4;                          // k-chunk (8 fp32 each)
    const int koff = c * 8;

    f32x4 accA00 = {0.f,0.f,0.f,0.f}, accA01 = {0.f,0.f,0.f,0.f}, accA11 = {0.f,0.f,0.f,0.f};
    f32x4 accB00 = {0.f,0.f,0.f,0.f}, accB01 = {0.f,0.f,0.f,0.f}, accB11 = {0.f,0.f,0.f,0.f};

#pragma unroll
    for (int s = 0; s < 4; ++s) {
        const int off0 = r0 * 128 + s * 32 + koff;     // row r0
        const int off1 = off0 + 16 * 128;              // row 16+r0

        // issue BOTH batches' 8x16B loads before any conversion/MFMA of this step
        const float4 Aa0 = *reinterpret_cast<const float4*>(xA + off0);
        const float4 Aa1 = *reinterpret_cast<const float4*>(xA + off0 + 4);
        const float4 Ab0 = *reinterpret_cast<const float4*>(xA + off1);
        const float4 Ab1 = *reinterpret_cast<const float4*>(xA + off1 + 4);
        const float4 Ba0 = *reinterpret_cast<const float4*>(xB + off0);
        const float4 Ba1 = *reinterpret_cast<const float4*>(xB + off0 + 4);
        const float4 Bb0 = *reinterpret_cast<const float4*>(xB + off1);
        const float4 Bb1 = *reinterpret_cast<const float4*>(xB + off1 + 4);

        bf16x8 fA0h, fA0l, fA1h, fA1l;
        split_hi_lo(Aa0, Aa1, fA0h, fA0l);
        split_hi_lo(Ab0, Ab1, fA1h, fA1l);
        accA00 = MFMA(fA0h, fA0h, accA00);
        accA00 = MFMA(fA0h, fA0l, accA00);
        accA00 = MFMA(fA0l, fA0h, accA00);
        accA01 = MFMA(fA0h, fA1h, accA01);
        accA01 = MFMA(fA0h, fA1l, accA01);
        accA01 = MFMA(fA0l, fA1h, accA01);
        accA11 = MFMA(fA1h, fA1h, accA11);
        accA11 = MFMA(fA1h, fA1l, accA11);
        accA11 = MFMA(fA1l, fA1h, accA11);

        bf16x8 fB0h, fB0l, fB1h, fB1l;
        split_hi_lo(Ba0, Ba1, fB0h, fB0l);
        split_hi_lo(Bb0, Bb1, fB1h, fB1l);
        accB00 = MFMA(fB0h, fB0h, accB00);
        accB00 = MFMA(fB0h, fB0l, accB00);
        accB00 = MFMA(fB0l, fB0h, accB00);
        accB01 = MFMA(fB0h, fB1h, accB01);
        accB01 = MFMA(fB0h, fB1l, accB01);
        accB01 = MFMA(fB0l, fB1h, accB01);
        accB11 = MFMA(fB1h, fB1h, accB11);
        accB11 = MFMA(fB1h, fB1l, accB11);
        accB11 = MFMA(fB1l, fB1h, accB11);
    }

    // ---- scatter into wave-local LDS pack (C/D: col j = lane&15, row = 4c+reg) ----
    const int j = lane & 15;
#pragma unroll
    for (int bb = 0; bb < 2; ++bb) {
        float* myPack = pack[wave][bb];
        const f32x4& a00 = bb ? accB00 : accA00;
        const f32x4& a01 = bb ? accB01 : accA01;
        const f32x4& a11 = bb ? accB11 : accA11;
#pragma unroll
        for (int reg = 0; reg < 4; ++reg) {
            const int i = (c << 2) + reg;
            const int base = 31 * i - (i * (i - 1)) / 2 - i - 1;   // p = base + j
            if (i < j) myPack[base + j] = a00[reg];                // G00 (i, j)
            myPack[base + 16 + j] = a01[reg];                      // G01 (i, 16+j)
            if (i < j) {
                const int I = 16 + i;
                const int baseI = 31 * I - (I * (I - 1)) / 2 - I - 1;
                myPack[baseI + 16 + j] = a11[reg];                 // G11 (16+i, 16+j)
            }
        }
    }
    // wave-local slab: all lanes' ds_writes complete with this wave's lgkmcnt
    asm volatile("s_waitcnt lgkmcnt(0)" ::: "memory");

    // ---- coalesced output: 124 contiguous float4 per batch ----
#pragma unroll
    for (int bb = 0; bb < 2; ++bb) {
        const float4* packed = reinterpret_cast<const float4*>(pack[wave][bb]);
        float4* outb = reinterpret_cast<float4*>(out + (size_t)(b0 + bb) * 496);
        outb[lane] = packed[lane];                           // f4 0..63
        if (lane < 60) outb[64 + lane] = packed[64 + lane];  // f4 64..123
    }
}

extern "C" void kernel_launch(void* const* d_in, const int* in_sizes, int n_in,
                              void* d_out, int out_size, void* d_ws, size_t ws_size,
                              hipStream_t stream) {
    const float* x = (const float*)d_in[0];
    float* out = (float*)d_out;
    const int batch = in_sizes[0] / (32 * 128);   // 16384
    const int grid = batch / 8;                   // 4 waves/block, 2 batches/wave
    soi_mfma2_kernel<<<grid, 256, 0, stream>>>(x, out);
}